// Round 10
// baseline (112.220 us; speedup 1.0000x reference)
//
#include <hip/hip_runtime.h>

#define NSYS 64
#define NAT  1000
#define NTOT (NSYS * NAT)          // 64000
#define MP   2200000               // MAX_PAIRS
#define CUT2 25.0f                 // cutoff^2
#define PADV 64000.0f              // padding_value = n
#define SCAN_BLOCKS 250            // 250 * 256 == 64000 exactly
#define CAP  104                   // per-row record capacity (max ~57 expected)
#define EB   512                   // eval blocks: 2 per CU, one round
#define LCN  1152                  // LDS atoms incl. tail overrun (j <= 1062)
#define NROWS 512                  // rows staged per emit block (min 512-row
                                   // pair sum ~6972 > POSB+CAP -> safe)
#define POSB  4096                 // output positions per emit block (2^12)
#define EMITB ((MP + POSB - 1) / POSB)   // 538

__device__ __forceinline__ float dist2f(float xi, float yi, float zi,
                                        float xj, float yj, float zj) {
    float dx = xi - xj, dy = yi - yj, dz = zi - zj;
    return fmaf(dz, dz, fmaf(dy, dy, dx * dx));
}

// popcount of mask over lanes strictly below me (2 VALU: v_mbcnt_lo/hi)
__device__ __forceinline__ int mbcnt(unsigned long long m) {
    unsigned lo = __builtin_amdgcn_mbcnt_lo((unsigned)m, 0u);
    return (int)__builtin_amdgcn_mbcnt_hi((unsigned)(m >> 32), lo);
}

// Emit one ballot group's kept pair (ascending-j order preserved).
__device__ __forceinline__ int emit_group(uint2* __restrict__ q, int running,
                                          bool k, int j, int r, float d,
                                          unsigned long long m) {
    if (k) {
        int rank = running + mbcnt(m);
        if (rank < CAP)
            q[rank] = make_uint2((unsigned)(j - r), __float_as_uint(d));
    }
    return running + (int)__popcll(m);
}

// Persistent eval (unchanged from R9): block b = (system, stripe); coords
// staged once as float4 SoA in LDS; 4x-unrolled inner loop; exact (s,i,j)
// rank via in-order ballots; per-row records (j-r, d2bits) + counts.
__global__ __launch_bounds__(1024) void k_eval(const float* __restrict__ coords,
                                               int* __restrict__ counts,
                                               uint2* __restrict__ qbuf) {
    __shared__ float4 lc[LCN];
    int s      = blockIdx.x >> 3;
    int stripe = blockIdx.x & 7;
    const float* cs = coords + s * (NAT * 3);
    for (int a = threadIdx.x; a < LCN; a += 1024)
        lc[a] = (a < NAT)
              ? make_float4(cs[3 * a], cs[3 * a + 1], cs[3 * a + 2], 0.0f)
              : make_float4(1.0e30f, 1.0e30f, 1.0e30f, 0.0f);
    __syncthreads();
    int w    = threadIdx.x >> 6;
    int lane = threadIdx.x & 63;
    int W    = stripe * 16 + w;
    for (int t = 0;; t++) {
        int r = ((t & 1) ? (127 - W) : W) + (t << 7);
        if (r >= NAT) { if (((t & 1) ? W : (127 - W)) + (t << 7) >= NAT) break; else continue; }
        float4 ci = lc[r];
        int grow = s * NAT + r;
        uint2* q = qbuf + (size_t)grow * CAP;
        int running = 0;
        int jb = r + 1;
        for (; jb + 255 < NAT; jb += 256) {
            int j = jb + lane;
            float4 c0 = lc[j];
            float4 c1 = lc[j + 64];
            float4 c2 = lc[j + 128];
            float4 c3 = lc[j + 192];
            float d0 = dist2f(ci.x, ci.y, ci.z, c0.x, c0.y, c0.z);
            float d1 = dist2f(ci.x, ci.y, ci.z, c1.x, c1.y, c1.z);
            float d2 = dist2f(ci.x, ci.y, ci.z, c2.x, c2.y, c2.z);
            float d3 = dist2f(ci.x, ci.y, ci.z, c3.x, c3.y, c3.z);
            bool k0 = d0 < CUT2;
            bool k1 = d1 < CUT2;
            bool k2 = d2 < CUT2;
            bool k3 = d3 < CUT2;
            unsigned long long m0 = __ballot(k0);
            unsigned long long m1 = __ballot(k1);
            unsigned long long m2 = __ballot(k2);
            unsigned long long m3 = __ballot(k3);
            running = emit_group(q, running, k0, j,       r, d0, m0);
            running = emit_group(q, running, k1, j + 64,  r, d1, m1);
            running = emit_group(q, running, k2, j + 128, r, d2, m2);
            running = emit_group(q, running, k3, j + 192, r, d3, m3);
        }
        for (; jb < NAT; jb += 64) {
            int j = jb + lane;
            float4 c0 = lc[j];
            float d0 = dist2f(ci.x, ci.y, ci.z, c0.x, c0.y, c0.z);
            bool k0 = (j < NAT) && (d0 < CUT2);
            unsigned long long m0 = __ballot(k0);
            running = emit_group(q, running, k0, j, r, d0, m0);
        }
        if (lane == 0) counts[grow] = running;
    }
}

// Level-1 scan: 250 blocks x 256 rows -> block-exclusive offs[] + block sums.
__global__ void k_scan_a(const int* __restrict__ counts, int* __restrict__ offs,
                         int* __restrict__ bsum) {
    __shared__ int tmp[256];
    int t = threadIdx.x;
    int g = blockIdx.x * 256 + t;
    int v = counts[g];
    tmp[t] = v;
    __syncthreads();
    for (int off = 1; off < 256; off <<= 1) {
        int u = (t >= off) ? tmp[t - off] : 0;
        __syncthreads();
        tmp[t] += u;
        __syncthreads();
    }
    offs[g] = tmp[t] - v;
    if (t == 255) bsum[blockIdx.x] = tmp[255];
}

// Scan bsum -> bpre_g[250] + total (bpre_g[250]); compute every emit block's
// start row r0g[b] with ZERO searching: row r owns blocks b where
// goff(r) <= b*POSB < goff(r+1) (unique owner). Tail blocks (b*POSB >= total)
// get r0 = NTOT from block 0 (disjoint from owner writes -> race-free).
__global__ __launch_bounds__(1024) void k_starts(const int* __restrict__ offs,
                                                 const int* __restrict__ bsum,
                                                 int* __restrict__ bpre_g,
                                                 int* __restrict__ r0g) {
    __shared__ int bpre[256];
    __shared__ int sh_tot;
    int t = threadIdx.x;
    int v = 0;
    if (t < 256) {
        v = (t < SCAN_BLOCKS) ? bsum[t] : 0;
        bpre[t] = v;
    }
    __syncthreads();
    for (int off = 1; off < 256; off <<= 1) {
        int u = 0;
        if (t < 256 && t >= off) u = bpre[t - off];
        __syncthreads();
        if (t < 256) bpre[t] += u;
        __syncthreads();
    }
    int incl = (t < 256) ? bpre[t] : 0;
    __syncthreads();
    if (t < 256) bpre[t] = incl - v;                 // exclusive prefix
    if (t == 255) sh_tot = incl;                     // grand total
    __syncthreads();
    int total = sh_tot;

    if (blockIdx.x == 0) {
        if (t < SCAN_BLOCKS) bpre_g[t] = bpre[t];
        if (t == SCAN_BLOCKS) bpre_g[SCAN_BLOCKS] = total;
        for (int b = t; b < EMITB; b += 1024)
            if (b * POSB >= total) r0g[b] = NTOT;    // tail: all-pad blocks
    }

    // owner writes: 8 blocks x 8000 rows, coalesced loads
    int base = blockIdx.x * 8000;
    for (int k = 0; k < 8000; k += 1024) {
        int r = base + k + t;
        int g0 = offs[r] + bpre[r >> 8];
        int g1 = (r + 1 < NTOT) ? offs[r + 1] + bpre[(r + 1) >> 8] : total;
        for (int b = (g0 + POSB - 1) >> 12; b * POSB < g1; b++)
            r0g[b] = r;
    }
}

// Position-indexed emit + pad: prologue is now just one coalesced lgoff
// staging pass (r0 precomputed, bpre_g prescanned) + ONE barrier.
// Out layout: [0)src [MP)dst [2MP)dst [3MP)src [4MP)d12 [5MP)d12 [6MP]npairs
__global__ __launch_bounds__(1024) void k_emit(const int* __restrict__ offs,
                                               const int* __restrict__ bpre_g,
                                               const int* __restrict__ r0g,
                                               const uint2* __restrict__ qbuf,
                                               float* __restrict__ out) {
    __shared__ int lgoff[NROWS + 1];
    int t = threadIdx.x;
    int total = bpre_g[SCAN_BLOCKS];                 // broadcast load
    int r0    = r0g[blockIdx.x];
    if (t <= NROWS) {
        int r = r0 + t;
        lgoff[t] = (r < NTOT) ? offs[r] + bpre_g[r >> 8] : total;
    }
    __syncthreads();

    if (blockIdx.x == 0 && t == 0) out[6 * MP] = (float)total;  // npairs
    int valid = total < MP ? total : MP;

    int p4 = blockIdx.x * POSB + t * 4;
    if (p4 >= MP) return;
    int k = 0;
    for (int step = 256; step; step >>= 1) {
        int nk = k + step;
        if (nk <= NROWS - 1 && lgoff[nk] <= p4) k = nk;
    }
    float fs[4], fd[4], dd[4];
#pragma unroll
    for (int e = 0; e < 4; e++) {
        int p = p4 + e;
        if (p < valid) {
            while (k < NROWS - 1 && lgoff[k + 1] <= p) k++;
            int row = r0 + k;
            int local = p - lgoff[k];
            if (local > CAP - 1) local = CAP - 1;    // count>CAP guard (P~0)
            uint2 rec = qbuf[(size_t)row * CAP + local];
            fs[e] = (float)row;
            fd[e] = (float)(row + (int)rec.x);
            dd[e] = __uint_as_float(rec.y);
        } else {
            fs[e] = PADV; fd[e] = PADV; dd[e] = CUT2;
        }
    }
    if (p4 + 4 <= MP) {
        float4 vs = {fs[0], fs[1], fs[2], fs[3]};
        float4 vd = {fd[0], fd[1], fd[2], fd[3]};
        float4 vv = {dd[0], dd[1], dd[2], dd[3]};
        *(float4*)(out + p4)          = vs;
        *(float4*)(out + MP + p4)     = vd;
        *(float4*)(out + 2 * MP + p4) = vd;
        *(float4*)(out + 3 * MP + p4) = vs;
        *(float4*)(out + 4 * MP + p4) = vv;
        *(float4*)(out + 5 * MP + p4) = vv;
    } else {
#pragma unroll
        for (int e = 0; e < 4; e++) {
            int p = p4 + e;
            if (p < MP) {
                out[p]          = fs[e];
                out[MP + p]     = fd[e];
                out[2 * MP + p] = fd[e];
                out[3 * MP + p] = fs[e];
                out[4 * MP + p] = dd[e];
                out[5 * MP + p] = dd[e];
            }
        }
    }
}

extern "C" void kernel_launch(void* const* d_in, const int* in_sizes, int n_in,
                              void* d_out, int out_size, void* d_ws, size_t ws_size,
                              hipStream_t stream) {
    const float* coords = (const float*)d_in[0];
    float* out = (float*)d_out;

    // Workspace: counts[64000] | offs[64000] | bsum[256] | bpre_g[256] |
    // r0g[544] | qbuf (8B-aligned: 129056 ints = 516224 B before it)
    int*   counts = (int*)d_ws;
    int*   offs   = counts + NTOT;
    int*   bsum   = offs + NTOT;
    int*   bpre_g = bsum + 256;
    int*   r0g    = bpre_g + 256;
    uint2* qbuf   = (uint2*)(r0g + 544);

    k_eval<<<EB, 1024, 0, stream>>>(coords, counts, qbuf);
    k_scan_a<<<SCAN_BLOCKS, 256, 0, stream>>>(counts, offs, bsum);
    k_starts<<<8, 1024, 0, stream>>>(offs, bsum, bpre_g, r0g);
    k_emit<<<EMITB, 1024, 0, stream>>>(offs, bpre_g, r0g, qbuf, out);
}